// Round 1
// 332.064 us; speedup vs baseline: 1.0148x; 1.0148x over previous
//
#include <hip/hip_runtime.h>
#include <hip/hip_bf16.h>
#include <math.h>

// Problem constants
#define BB 4096
#define DD 2048
#define HH 2048

typedef __bf16 bf16x8 __attribute__((ext_vector_type(8)));
typedef float f32x4 __attribute__((ext_vector_type(4)));

__device__ __forceinline__ void async16(const void* g, void* l) {
  __builtin_amdgcn_global_load_lds(
      (const __attribute__((address_space(1))) unsigned int*)g,
      (__attribute__((address_space(3))) unsigned int*)l,
      16, 0, 0);
}

__device__ __forceinline__ float sigmoidf_(float x) {
  return 1.0f / (1.0f + __expf(-x));
}
__device__ __forceinline__ float tanhf_(float x) {
  float t = __expf(-2.0f * fabsf(x));
  return copysignf((1.0f - t) / (1.0f + t), x);
}

__device__ __forceinline__ void store_bf8(__hip_bfloat16* dst, const float* v) {
  union { __hip_bfloat16 b[8]; uint4 u; } p;
#pragma unroll
  for (int e = 0; e < 8; e++) p.b[e] = __float2bfloat16(v[e]);
  *(uint4*)dst = p.u;
}

// ---------------------------------------------------------------------------
// bias[g][c] = b_g[c] + rb_g[c],  g in {z,i,f,o}
__global__ void prep_bias(const float* __restrict__ bz, const float* __restrict__ bi,
                          const float* __restrict__ bf, const float* __restrict__ bo,
                          const float* __restrict__ rbz, const float* __restrict__ rbi,
                          const float* __restrict__ rbf, const float* __restrict__ rbo,
                          float* __restrict__ bias) {
  int i = blockIdx.x * 256 + threadIdx.x;
  if (i < 2048) {
    bias[0 * 2048 + i] = bz[i] + rbz[i];
    bias[1 * 2048 + i] = bi[i] + rbi[i];
    bias[2 * 2048 + i] = bf[i] + rbf[i];
    bias[3 * 2048 + i] = bo[i] + rbo[i];
  }
}

// ---------------------------------------------------------------------------
// WT2 granule ((gn*16 + jt)*32 + ks)*128 + j*4 + pc  (16B granules), holding
// W/R[n][ks*32 + c*8 .. +8][jt*32+j] bf16x8, c = pc ^ ((j>>1)&3).
// Direct global gather (no LDS): per e-step a wave reads 4 rows x 64B.
__global__ __launch_bounds__(256) void prep_w(
    const float* __restrict__ Wz, const float* __restrict__ Wi,
    const float* __restrict__ Wf, const float* __restrict__ Wo,
    const float* __restrict__ Rz, const float* __restrict__ Ri,
    const float* __restrict__ Rf, const float* __restrict__ Ro,
    __hip_bfloat16* __restrict__ WT2) {
  const int jt = blockIdx.x;    // 16 j-tiles of 32
  const int ksg = blockIdx.y;   // 8 groups of 128 k
  const int gn = blockIdx.z;    // g*4 + n
  const int g = gn >> 2, nn = gn & 3;
  const float* src;
  if (ksg < 4) src = (g == 0 ? Wz : g == 1 ? Wi : g == 2 ? Wf : Wo);
  else         src = (g == 0 ? Rz : g == 1 ? Ri : g == 2 ? Rf : Ro);
  const int t = threadIdx.x;
#pragma unroll
  for (int q = 0; q < 2; q++) {
    int u = t + q * 256;
    int ksl = u >> 7, j = (u >> 2) & 31, pc = u & 3;
    int c = pc ^ ((j >> 1) & 3);
    int kr = (ksg & 3) * 128 + ksl * 32 + c * 8;
    const float* s0 = src + ((size_t)nn * 512 + kr) * 512 + jt * 32 + j;
    float v[8];
#pragma unroll
    for (int e = 0; e < 8; e++) v[e] = s0[(size_t)e * 512];
    size_t gr = ((size_t)(gn * 16 + jt) * 32 + ksg * 4 + ksl) * 128 + j * 4 + pc;
    store_bf8(WT2 + gr * 8, v);
  }
}

// ---------------------------------------------------------------------------
// Per row: LN -> conv3 -> SiLU. Emits tiled+swizzled bf16:
//  xh2 granule ((mb*4+n)*32 + ks)*512 + rl*4 + pc : ks<16 = x, ks>=16 = h
//  xc2 granule ((mb*4+n)*16 + ks)*512 + rl*4 + pc : SiLU(conv(LN(x)))
__global__ __launch_bounds__(256) void prep_act(
    const float* __restrict__ x, const float* __restrict__ h,
    const float* __restrict__ lg, const float* __restrict__ lb,
    const float* __restrict__ cw, const float* __restrict__ cb,
    __hip_bfloat16* __restrict__ xh2, __hip_bfloat16* __restrict__ xc2) {
  const int r = blockIdx.x, t = threadIdx.x, l = t & 63;
  const int mb = r >> 7, rl = r & 127, swz = (rl >> 1) & 3;
  const int n = t >> 6, ktl = (t >> 2) & 15, pc = (t & 3) ^ swz;
  __shared__ float red[8];
  __shared__ float edge[256][2];
  const float* xr = x + (size_t)r * 2048;
  const float* hr = h + (size_t)r * 2048;
  float4 v0 = ((const float4*)xr)[t * 2];
  float4 v1 = ((const float4*)xr)[t * 2 + 1];
  float vv[8] = {v0.x, v0.y, v0.z, v0.w, v1.x, v1.y, v1.z, v1.w};
  float s = 0.f, s2 = 0.f;
#pragma unroll
  for (int e = 0; e < 8; e++) { s += vv[e]; s2 += vv[e] * vv[e]; }
#pragma unroll
  for (int off = 32; off > 0; off >>= 1) {
    s += __shfl_down(s, off);
    s2 += __shfl_down(s2, off);
  }
  const int w = t >> 6;
  if (l == 0) { red[w] = s; red[4 + w] = s2; }
  __syncthreads();
  const float mu = (red[0] + red[1] + red[2] + red[3]) * (1.0f / 2048.0f);
  const float var = (red[4] + red[5] + red[6] + red[7]) * (1.0f / 2048.0f) - mu * mu;
  const float rs = rsqrtf(var + 1e-5f);

  float4 h0 = ((const float4*)hr)[t * 2];
  float4 h1 = ((const float4*)hr)[t * 2 + 1];
  float hh[8] = {h0.x, h0.y, h0.z, h0.w, h1.x, h1.y, h1.z, h1.w};
  float4 g0 = ((const float4*)lg)[t * 2], g1 = ((const float4*)lg)[t * 2 + 1];
  float4 b0 = ((const float4*)lb)[t * 2], b1 = ((const float4*)lb)[t * 2 + 1];
  float gg[8] = {g0.x, g0.y, g0.z, g0.w, g1.x, g1.y, g1.z, g1.w};
  float bb[8] = {b0.x, b0.y, b0.z, b0.w, b1.x, b1.y, b1.z, b1.w};
  float fr[8];
#pragma unroll
  for (int e = 0; e < 8; e++) fr[e] = (vv[e] - mu) * rs * gg[e] + bb[e];

  const size_t bx = ((size_t)(mb * 4 + n) * 32 + ktl) * 512 + rl * 4 + pc;
  const size_t bh = ((size_t)(mb * 4 + n) * 32 + 16 + ktl) * 512 + rl * 4 + pc;
  store_bf8(xh2 + bx * 8, vv);
  store_bf8(xh2 + bh * 8, hh);

  edge[t][0] = fr[6]; edge[t][1] = fr[7];
  __syncthreads();
  float p6 = __shfl_up(fr[6], 1);
  float p7 = __shfl_up(fr[7], 1);
  if (l == 0) {
    p6 = (t > 0) ? edge[t - 1][0] : 0.f;
    p7 = (t > 0) ? edge[t - 1][1] : 0.f;
  }
  const float w0 = cw[0], w1 = cw[1], w2 = cw[2], cbv = cb[0];
  float sc[8];
  {
    float xc0 = w0 * p6 + w1 * p7 + w2 * fr[0] + cbv;
    float xc1 = w0 * p7 + w1 * fr[0] + w2 * fr[1] + cbv;
    sc[0] = xc0 * sigmoidf_(xc0);
    sc[1] = xc1 * sigmoidf_(xc1);
  }
#pragma unroll
  for (int e = 2; e < 8; e++) {
    float xc = w0 * fr[e - 2] + w1 * fr[e - 1] + w2 * fr[e] + cbv;
    sc[e] = xc * sigmoidf_(xc);
  }
  const size_t bc = ((size_t)(mb * 4 + n) * 16 + ktl) * 512 + rl * 4 + pc;
  store_bf8(xc2 + bc * 8, sc);
}

// ---------------------------------------------------------------------------
// Fused 4-gate block GEMM + sLSTM epilogue.
// Grid 1024 blocks (1D, XCD-swizzled), 512 threads = 8 waves.
// Logical tile: mb (128 rows) x jt (64 cols) x n (512-col block), 4 gates.
// Wave w: pair = w>>2 (0:(z,o), 1:(i,f)), mhalf = (w>>1)&1, jhalf = w&1.
// BK=32 double-buffered: per stage the block stages 32KB (A 8 + C 8 + B 16)
// and runs 128 MFMA. Counted s_waitcnt vmcnt(4|3) keeps the next stage's
// global_load_lds in flight across the barrier (never drains to 0 in-loop).
// LDS 2 x 32KB = 64KB -> 2 blocks/CU = 16 waves.
__global__ __launch_bounds__(512, 4) void gemm_fused(
    const __hip_bfloat16* __restrict__ xh2, const __hip_bfloat16* __restrict__ xc2,
    const __hip_bfloat16* __restrict__ WT2, const float* __restrict__ bias,
    const float* __restrict__ c_prev, float* __restrict__ out) {
  // per-stage buffer map (offset (ks&1)*32768):
  //   [0,8K)   A = x (ks<16) / h (ks>=16)   [128m][64B swz]
  //   [8K,16K) C = xc (ks<16 only)          [128m][64B swz]
  //   [16K,32K) B  [4g][2jtw][32j][64B swz]
  // epilogue union: zo bf16 [2][128][72] = 36,864B
  __shared__ __attribute__((aligned(16))) char smem[65536];
  __hip_bfloat16* zo = (__hip_bfloat16*)smem;

  // XCD-aware bijective swizzle (1024 % 8 == 0): physical block o -> logical
  // lid = (o%8)*128 + o/8, so each XCD gets one n, 4 jt, all 32 mb ->
  // B slices (2MB) stay L2-resident, A slices get 4-way L2 reuse.
  const int o = blockIdx.x;
  const int lid = (o & 7) * 128 + (o >> 3);
  const int mb = lid & 31, jt = (lid >> 5) & 7, n = lid >> 8;

  const int t = threadIdx.x, w = t >> 6, l = t & 63;
  const int pair = w >> 2, mhalf = (w >> 1) & 1, jhalf = w & 1;
  const int lj = l & 15;

  // staging sources (per stage ks: A/C advance 8KB, B advances 2KB)
  const char* pA = (const char*)xh2 + (size_t)(mb * 4 + n) * 262144 + t * 16;
  const char* pC = (const char*)xc2 + (size_t)(mb * 4 + n) * 131072 + t * 16;
  const int bg = t >> 7, br = t & 127;  // B: thread covers gate bg, granule br
  const char* pB = (const char*)WT2 +
      ((size_t)((bg * 4 + n) * 16 + jt * 2)) * 65536 + br * 16;
  const int dAo = t * 16;
  const int dBo = 16384 + bg * 4096 + br * 16;

  // frag byte offset (swizzled): row lj -> lj*64 + (chunk ^ ((lj>>1)&3))*16
  const int fo = lj * 64 + (((l >> 4) ^ ((lj >> 1) & 3)) * 16);
  const int g0 = pair ? 1 : 0, g1 = pair ? 2 : 3;

  f32x4 acc[4][2][2] = {};

  // prologue: stage 0 into buf0 (4 loads/thread)
  {
    char* nb = smem;
    async16(pA, nb + dAo);
    async16(pC, nb + 8192 + dAo);
    async16(pB, nb + dBo);
    async16(pB + 65536, nb + dBo + 2048);
  }

  for (int ks = 0; ks < 32; ++ks) {
    const int nxt = ks + 1;
    if (nxt < 16) {
      char* nb = smem + (nxt & 1) * 32768;
      async16(pA + (size_t)nxt * 8192, nb + dAo);
      async16(pC + (size_t)nxt * 8192, nb + 8192 + dAo);
      async16(pB + (size_t)nxt * 2048, nb + dBo);
      async16(pB + (size_t)nxt * 2048 + 65536, nb + dBo + 2048);
      asm volatile("s_waitcnt vmcnt(4)" ::: "memory");  // stage ks landed
    } else if (nxt < 32) {
      char* nb = smem + (nxt & 1) * 32768;
      async16(pA + (size_t)nxt * 8192, nb + dAo);
      async16(pB + (size_t)nxt * 2048, nb + dBo);
      async16(pB + (size_t)nxt * 2048 + 65536, nb + dBo + 2048);
      asm volatile("s_waitcnt vmcnt(3)" ::: "memory");  // stage ks landed
    } else {
      asm volatile("s_waitcnt vmcnt(0)" ::: "memory");  // drain last stage
    }
    __builtin_amdgcn_s_barrier();          // all waves: stage ks ready
    __builtin_amdgcn_sched_barrier(0);     // no ds_read hoists above this

    const char* cb = smem + (ks & 1) * 32768;
    const char* Ab = ((ks < 16 && pair) ? cb + 8192 : cb) + mhalf * 4096 + fo;
    const char* Bb = cb + 16384 + jhalf * 2048 + fo;
    bf16x8 af[4];
#pragma unroll
    for (int s = 0; s < 4; ++s)
      af[s] = *(const bf16x8*)(Ab + s * 1024);
#pragma unroll
    for (int sj = 0; sj < 2; ++sj) {
      bf16x8 b0 = *(const bf16x8*)(Bb + g0 * 4096 + sj * 1024);
      bf16x8 b1 = *(const bf16x8*)(Bb + g1 * 4096 + sj * 1024);
#pragma unroll
      for (int s = 0; s < 4; ++s) {
        acc[s][sj][0] = __builtin_amdgcn_mfma_f32_16x16x32_bf16(af[s], b0, acc[s][sj][0], 0, 0, 0);
        acc[s][sj][1] = __builtin_amdgcn_mfma_f32_16x16x32_bf16(af[s], b1, acc[s][sj][1], 0, 0, 0);
      }
    }
    __builtin_amdgcn_sched_barrier(0);     // no ds_read/MFMA sinks below
    __builtin_amdgcn_s_barrier();          // all waves done reading buf ks&1
    __builtin_amdgcn_sched_barrier(0);
  }

  // ---- Epilogue. C/D 16x16: col = lane&15, row = (lane>>4)*4 + reg.
  const int r0 = (l >> 4) * 4;
  const int colb = n * 512 + jt * 64;
  __syncthreads();
  if (pair == 0) {
#pragma unroll
    for (int sj = 0; sj < 2; ++sj) {
      const int jc = jhalf * 32 + sj * 16 + lj;
      const float bz_ = bias[colb + jc];
      const float bo_ = bias[3 * 2048 + colb + jc];
#pragma unroll
      for (int s = 0; s < 4; ++s) {
#pragma unroll
        for (int rr = 0; rr < 4; ++rr) {
          const int rl = mhalf * 64 + s * 16 + r0 + rr;
          zo[rl * 72 + jc] = __float2bfloat16(tanhf_(acc[s][sj][0][rr] + bz_));
          zo[(128 + rl) * 72 + jc] = __float2bfloat16(sigmoidf_(acc[s][sj][1][rr] + bo_));
        }
      }
    }
  }
  __syncthreads();
  if (pair == 1) {
    const size_t HC = (size_t)BB * HH;
#pragma unroll
    for (int sj = 0; sj < 2; ++sj) {
      const int jc = jhalf * 32 + sj * 16 + lj;
      const int col = colb + jc;
      const float bi_ = bias[1 * 2048 + col];
      const float bf_ = bias[2 * 2048 + col];
#pragma unroll
      for (int s = 0; s < 4; ++s) {
#pragma unroll
        for (int rr = 0; rr < 4; ++rr) {
          const int rl = mhalf * 64 + s * 16 + r0 + rr;
          const int row = mb * 128 + rl;
          const float z  = __bfloat162float(zo[rl * 72 + jc]);
          const float og = __bfloat162float(zo[(128 + rl) * 72 + jc]);
          const float ig = sigmoidf_(acc[s][sj][0][rr] + bi_);
          const float fg = sigmoidf_(acc[s][sj][1][rr] + bf_);
          const float cp = c_prev[(size_t)row * 2048 + col];
          const float c = fg * cp + ig * z;
          const float hv = og * tanhf_(c);
          out[(size_t)row * 2048 + col] = hv;
          out[HC + (size_t)row * 2048 + col] = c;
        }
      }
    }
  }
}

// ---------------------------------------------------------------------------
extern "C" void kernel_launch(void* const* d_in, const int* in_sizes, int n_in,
                              void* d_out, int out_size, void* d_ws, size_t ws_size,
                              hipStream_t stream) {
  const float* x      = (const float*)d_in[0];
  const float* h_prev = (const float*)d_in[1];
  const float* c_prev = (const float*)d_in[2];
  const float* ln_g   = (const float*)d_in[3];
  const float* ln_b   = (const float*)d_in[4];
  const float* conv_w = (const float*)d_in[5];
  const float* conv_b = (const float*)d_in[6];
  const float* Wz = (const float*)d_in[7];
  const float* bz = (const float*)d_in[8];
  const float* Wi = (const float*)d_in[9];
  const float* bi = (const float*)d_in[10];
  const float* Wf = (const float*)d_in[11];
  const float* bf = (const float*)d_in[12];
  const float* Wo = (const float*)d_in[13];
  const float* bo = (const float*)d_in[14];
  const float* Rz = (const float*)d_in[15];
  const float* rbz = (const float*)d_in[16];
  const float* Ri = (const float*)d_in[17];
  const float* rbi = (const float*)d_in[18];
  const float* Rf = (const float*)d_in[19];
  const float* rbf = (const float*)d_in[20];
  const float* Ro = (const float*)d_in[21];
  const float* rbo = (const float*)d_in[22];
  float* out = (float*)d_out;

  char* ws = (char*)d_ws;
  __hip_bfloat16* xh2 = (__hip_bfloat16*)(ws);                       // 32 MiB
  __hip_bfloat16* xc2 = (__hip_bfloat16*)(ws + 33554432);            // 16 MiB
  __hip_bfloat16* WT2 = (__hip_bfloat16*)(ws + 33554432 + 16777216); // 16 MiB
  float* bias         = (float*)(ws + 33554432 + 2 * 16777216);      // 32 KiB

  prep_bias<<<8, 256, 0, stream>>>(bz, bi, bf, bo, rbz, rbi, rbf, rbo, bias);
  prep_w<<<dim3(16, 8, 16), 256, 0, stream>>>(Wz, Wi, Wf, Wo, Rz, Ri, Rf, Ro, WT2);
  prep_act<<<BB, 256, 0, stream>>>(x, h_prev, ln_g, ln_b, conv_w, conv_b, xh2, xc2);
  gemm_fused<<<1024, 512, 0, stream>>>(xh2, xc2, WT2, bias, c_prev, out);
}